// Round 3
// baseline (537.634 us; speedup 1.0000x reference)
//
#include <hip/hip_runtime.h>
#include <hip/hip_bf16.h>

#define N_FULL 262144
#define M_POOL 131072

typedef __attribute__((ext_vector_type(4))) float f32x4;
typedef __attribute__((ext_vector_type(8))) short bf16x8;
typedef __attribute__((ext_vector_type(8))) unsigned short u16x8;

static __device__ __forceinline__ unsigned short f2b(float f) {
    __hip_bfloat16 b = __float2bfloat16(f);
    return *reinterpret_cast<unsigned short*>(&b);
}
static __device__ __forceinline__ float b2f(unsigned short u) {
    unsigned int x = ((unsigned int)u) << 16;
    return __uint_as_float(x);
}

// barrier that does NOT drain vmcnt: LDS-visibility wait + raw barrier + reorder fence
static __device__ __forceinline__ void lds_barrier() {
    asm volatile("s_waitcnt lgkmcnt(0)" ::: "memory");
    __builtin_amdgcn_s_barrier();
    asm volatile("" ::: "memory");
}

// ---------- pack W2/W3 into MFMA B-fragment order ----------
// Wp[k][q][t][lane][j] = W[k][q*32 + (lane>>4)*8 + j][t*16 + (lane&15)]
template<int CT>
__global__ __launch_bounds__(256) void pack_w_kernel(const float* __restrict__ W,
                                                     unsigned short* __restrict__ Wp) {
    int i = blockIdx.x * 256 + threadIdx.x;
    const int total = 27 * 2 * CT * 64 * 8;
    if (i >= total) return;
    int j = i & 7;
    int l = (i >> 3) & 63;
    int t = (i >> 9) % CT;
    int q = (i / (512 * CT)) & 1;
    int k = i / (1024 * CT);
    int cin = q * 32 + (l >> 4) * 8 + j;
    int cout = t * 16 + (l & 15);
    Wp[i] = f2b(W[(k * 64 + cin) * (CT * 16) + cout]);
}

// ---------- pack W1 (Cin=3) with 4 taps folded into K=32 ----------
__global__ __launch_bounds__(256) void pack_w1_kernel(const float* __restrict__ W1,
                                                      unsigned short* __restrict__ Wp) {
    int i = blockIdx.x * 256 + threadIdx.x;
    const int total = 7 * 4 * 64 * 8;
    if (i >= total) return;
    int j = i & 7;
    int l = (i >> 3) & 63;
    int t = (i >> 9) & 3;
    int kb = i >> 11;
    int tap = kb * 4 + (l >> 4);
    float v = 0.f;
    if (tap < 27 && j < 3) v = W1[(tap * 3 + j) * 64 + t * 16 + (l & 15)];
    Wp[i] = f2b(v);
}

// ---------- conv1: MFMA, 4 taps per K=32, pipelined, fused stats ----------
__global__ __launch_bounds__(256) void conv1_mfma_kernel(const float* __restrict__ feats,
                                                         const unsigned short* __restrict__ Wp,
                                                         const int* __restrict__ nbr,
                                                         unsigned short* __restrict__ Y,
                                                         float* __restrict__ sums, int R) {
    __shared__ unsigned short lw[2][2048];
    __shared__ float psum[4][64], psq[4][64];
    const int tid = threadIdx.x;
    const int wave = tid >> 6;
    const int lane = tid & 63;
    const int l16 = lane & 15;
    const int lq = lane >> 4;
    const int rowbase = blockIdx.x * 128 + wave * 32;

    f32x4 acc[2][4];
    #pragma unroll
    for (int s = 0; s < 2; ++s)
        #pragma unroll
        for (int t = 0; t < 4; ++t)
            #pragma unroll
            for (int g = 0; g < 4; ++g) acc[s][t][g] = 0.f;
    bf16x8 zf;
    #pragma unroll
    for (int j = 0; j < 8; ++j) zf[j] = 0;

    const int4* wsrc = reinterpret_cast<const int4*>(Wp);
    // prolog: B[0], idx[0] + A[0], idx[1]
    int4 breg = wsrc[tid];
    int idxc[2], idxn[2];
    #pragma unroll
    for (int s = 0; s < 2; ++s) idxc[s] = nbr[lq * R + rowbase + s * 16 + l16];
    bf16x8 af[2], afn[2];
    #pragma unroll
    for (int s = 0; s < 2; ++s) {
        int ic = idxc[s] >= 0 ? idxc[s] : 0;
        af[s] = zf;
        af[s][0] = (short)f2b(feats[ic * 3 + 0]);
        af[s][1] = (short)f2b(feats[ic * 3 + 1]);
        af[s][2] = (short)f2b(feats[ic * 3 + 2]);
    }
    #pragma unroll
    for (int s = 0; s < 2; ++s) idxn[s] = nbr[(4 + lq) * R + rowbase + s * 16 + l16];

    for (int kb = 0; kb < 7; ++kb) {
        const int p = kb & 1;
        reinterpret_cast<int4*>(lw[p])[tid] = breg;                // commit B[kb]
        if (kb + 1 < 7) breg = wsrc[(kb + 1) * 256 + tid];         // B[kb+1] in flight
        int idxn2[2];
        if (kb + 1 < 7) {                                          // gather A[kb+1]
            #pragma unroll
            for (int s = 0; s < 2; ++s) {
                int ic = idxn[s] >= 0 ? idxn[s] : 0;
                afn[s] = zf;
                afn[s][0] = (short)f2b(feats[ic * 3 + 0]);
                afn[s][1] = (short)f2b(feats[ic * 3 + 1]);
                afn[s][2] = (short)f2b(feats[ic * 3 + 2]);
            }
        }
        if (kb + 2 < 7) {                                          // idx[kb+2] in flight
            int tap = (kb + 2) * 4 + lq;
            #pragma unroll
            for (int s = 0; s < 2; ++s)
                idxn2[s] = (tap < 27) ? nbr[tap * R + rowbase + s * 16 + l16] : -1;
        }
        lds_barrier();
        #pragma unroll
        for (int s = 0; s < 2; ++s) if (idxc[s] < 0) af[s] = zf;
        #pragma unroll
        for (int t = 0; t < 4; ++t) {
            bf16x8 bfr = *reinterpret_cast<const bf16x8*>(&lw[p][(t * 64 + lane) * 8]);
            #pragma unroll
            for (int s = 0; s < 2; ++s)
                acc[s][t] = __builtin_amdgcn_mfma_f32_16x16x32_bf16(af[s], bfr, acc[s][t], 0, 0, 0);
        }
        #pragma unroll
        for (int s = 0; s < 2; ++s) { af[s] = afn[s]; idxc[s] = idxn[s]; idxn[s] = idxn2[s]; }
    }
    // kb=6 handles taps 24..26 (lq==3 masked via idx=-1 at pack+load)
    #pragma unroll
    for (int t = 0; t < 4; ++t) {
        float s1 = 0.f, s2 = 0.f;
        #pragma unroll
        for (int s = 0; s < 2; ++s)
            #pragma unroll
            for (int g = 0; g < 4; ++g) {
                float v = acc[s][t][g];
                s1 += v; s2 += v * v;
                Y[(rowbase + s * 16 + lq * 4 + g) * 64 + t * 16 + l16] = f2b(v);
            }
        s1 += __shfl_xor(s1, 16); s2 += __shfl_xor(s2, 16);
        s1 += __shfl_xor(s1, 32); s2 += __shfl_xor(s2, 32);
        if (lq == 0) { psum[wave][t * 16 + l16] = s1; psq[wave][t * 16 + l16] = s2; }
    }
    __syncthreads();
    if (tid < 64) {
        float s1 = 0.f, s2 = 0.f;
        #pragma unroll
        for (int w = 0; w < 4; ++w) { s1 += psum[w][tid]; s2 += psq[w][tid]; }
        atomicAdd(&sums[tid], s1);
        atomicAdd(&sums[64 + tid], s2);
    }
}

// ---------- MFMA sparse conv: Cin=64, Cout=CT*16, single-barrier pipeline ----------
template<int CT>
__global__ __launch_bounds__(256) void conv_mfma_kernel(const unsigned short* __restrict__ X,
                                                        const unsigned short* __restrict__ Wp,
                                                        const int* __restrict__ nbr,
                                                        unsigned short* __restrict__ Y,
                                                        float* __restrict__ sums, int Nout) {
    constexpr int C = CT * 16;
    constexpr int BI4 = CT / 2;                     // int4 per thread per tap
    __shared__ unsigned short lw[2][CT * 1024];     // double-buffered B tap
    __shared__ float psum[4][C], psq[4][C];
    const int tid = threadIdx.x;
    const int wave = tid >> 6;
    const int lane = tid & 63;
    const int l16 = lane & 15;
    const int lq = lane >> 4;
    const int rowbase = blockIdx.x * 128 + wave * 32;

    f32x4 acc[2][CT];
    #pragma unroll
    for (int s = 0; s < 2; ++s)
        #pragma unroll
        for (int t = 0; t < CT; ++t)
            #pragma unroll
            for (int g = 0; g < 4; ++g) acc[s][t][g] = 0.f;
    bf16x8 zf;
    #pragma unroll
    for (int j = 0; j < 8; ++j) zf[j] = 0;

    const int4* wsrc = reinterpret_cast<const int4*>(Wp);
    int4 breg[BI4];
    #pragma unroll
    for (int i = 0; i < BI4; ++i) breg[i] = wsrc[i * 256 + tid];
    int idxc[2], idxn[2];
    #pragma unroll
    for (int s = 0; s < 2; ++s) idxc[s] = nbr[rowbase + s * 16 + l16];
    bf16x8 af[2][2], afn[2][2];
    #pragma unroll
    for (int s = 0; s < 2; ++s) {
        int ic = idxc[s] >= 0 ? idxc[s] : 0;
        #pragma unroll
        for (int q = 0; q < 2; ++q)
            af[s][q] = *reinterpret_cast<const bf16x8*>(X + (size_t)ic * 64 + q * 32 + lq * 8);
    }
    #pragma unroll
    for (int s = 0; s < 2; ++s) idxn[s] = nbr[Nout + rowbase + s * 16 + l16];

    for (int k = 0; k < 27; ++k) {
        const int p = k & 1;
        #pragma unroll
        for (int i = 0; i < BI4; ++i)
            reinterpret_cast<int4*>(lw[p])[i * 256 + tid] = breg[i];   // commit B[k]
        if (k + 1 < 27) {
            #pragma unroll
            for (int i = 0; i < BI4; ++i)
                breg[i] = wsrc[(k + 1) * (CT * 128) + i * 256 + tid];  // B[k+1] in flight
            #pragma unroll
            for (int s = 0; s < 2; ++s) {                              // A[k+1] gather (idx arrived)
                int ic = idxn[s] >= 0 ? idxn[s] : 0;
                #pragma unroll
                for (int q = 0; q < 2; ++q)
                    afn[s][q] = *reinterpret_cast<const bf16x8*>(X + (size_t)ic * 64 + q * 32 + lq * 8);
            }
        }
        int idxn2[2];
        if (k + 2 < 27) {                                              // idx[k+2] in flight
            #pragma unroll
            for (int s = 0; s < 2; ++s)
                idxn2[s] = nbr[(k + 2) * Nout + rowbase + s * 16 + l16];
        }
        lds_barrier();
        #pragma unroll
        for (int s = 0; s < 2; ++s)
            if (idxc[s] < 0) { af[s][0] = zf; af[s][1] = zf; }
        #pragma unroll
        for (int t = 0; t < CT; ++t) {
            #pragma unroll
            for (int q = 0; q < 2; ++q) {
                bf16x8 bfr = *reinterpret_cast<const bf16x8*>(&lw[p][((q * CT + t) * 64 + lane) * 8]);
                #pragma unroll
                for (int s = 0; s < 2; ++s)
                    acc[s][t] = __builtin_amdgcn_mfma_f32_16x16x32_bf16(af[s][q], bfr, acc[s][t], 0, 0, 0);
            }
        }
        #pragma unroll
        for (int s = 0; s < 2; ++s) {
            af[s][0] = afn[s][0]; af[s][1] = afn[s][1];
            idxc[s] = idxn[s]; idxn[s] = idxn2[s];
        }
    }
    #pragma unroll
    for (int t = 0; t < CT; ++t) {
        float s1 = 0.f, s2 = 0.f;
        #pragma unroll
        for (int s = 0; s < 2; ++s)
            #pragma unroll
            for (int g = 0; g < 4; ++g) {
                float v = acc[s][t][g];
                s1 += v; s2 += v * v;
                Y[(rowbase + s * 16 + lq * 4 + g) * C + t * 16 + l16] = f2b(v);
            }
        s1 += __shfl_xor(s1, 16); s2 += __shfl_xor(s2, 16);
        s1 += __shfl_xor(s1, 32); s2 += __shfl_xor(s2, 32);
        if (lq == 0) { psum[wave][t * 16 + l16] = s1; psq[wave][t * 16 + l16] = s2; }
    }
    __syncthreads();
    if (tid < C) {
        float s1 = 0.f, s2 = 0.f;
        #pragma unroll
        for (int w = 0; w < 4; ++w) { s1 += psum[w][tid]; s2 += psq[w][tid]; }
        atomicAdd(&sums[tid], s1);
        atomicAdd(&sums[C + tid], s2);
    }
}

// ---------- normalize + relu : bf16 in -> bf16 out ----------
template<int C>
__global__ __launch_bounds__(256) void norm_bf16_kernel(const unsigned short* __restrict__ Y,
                                                        const float* __restrict__ sums,
                                                        unsigned short* __restrict__ Xb, int R) {
    __shared__ float lmu[C], lrs[C];
    if (threadIdx.x < C) {
        float m = sums[threadIdx.x] / (float)R;
        float v = sums[C + threadIdx.x] / (float)R - m * m;
        lmu[threadIdx.x] = m;
        lrs[threadIdx.x] = rsqrtf(fmaxf(v, 0.f) + 1e-5f);
    }
    __syncthreads();
    const int total = R * C / 8;
    for (int i = blockIdx.x * 256 + threadIdx.x; i < total; i += gridDim.x * 256) {
        u16x8 v = reinterpret_cast<const u16x8*>(Y)[i];
        int cb = (i * 8) & (C - 1);
        u16x8 o;
        #pragma unroll
        for (int j = 0; j < 8; ++j) {
            float f = b2f(v[j]);
            o[j] = f2b(fmaxf((f - lmu[cb + j]) * lrs[cb + j], 0.f));
        }
        reinterpret_cast<u16x8*>(Xb)[i] = o;
    }
}

// ---------- normalize + relu : bf16 in -> f32 out (final) ----------
template<int C>
__global__ __launch_bounds__(256) void norm_f32_kernel(const unsigned short* __restrict__ Y,
                                                       const float* __restrict__ sums,
                                                       float* __restrict__ Out, int R) {
    __shared__ float lmu[C], lrs[C];
    if (threadIdx.x < C) {
        float m = sums[threadIdx.x] / (float)R;
        float v = sums[C + threadIdx.x] / (float)R - m * m;
        lmu[threadIdx.x] = m;
        lrs[threadIdx.x] = rsqrtf(fmaxf(v, 0.f) + 1e-5f);
    }
    __syncthreads();
    const int total = R * C / 8;
    for (int i = blockIdx.x * 256 + threadIdx.x; i < total; i += gridDim.x * 256) {
        u16x8 v = reinterpret_cast<const u16x8*>(Y)[i];
        int cb = (i * 8) & (C - 1);
        float4 o0, o1;
        o0.x = fmaxf((b2f(v[0]) - lmu[cb + 0]) * lrs[cb + 0], 0.f);
        o0.y = fmaxf((b2f(v[1]) - lmu[cb + 1]) * lrs[cb + 1], 0.f);
        o0.z = fmaxf((b2f(v[2]) - lmu[cb + 2]) * lrs[cb + 2], 0.f);
        o0.w = fmaxf((b2f(v[3]) - lmu[cb + 3]) * lrs[cb + 3], 0.f);
        o1.x = fmaxf((b2f(v[4]) - lmu[cb + 4]) * lrs[cb + 4], 0.f);
        o1.y = fmaxf((b2f(v[5]) - lmu[cb + 5]) * lrs[cb + 5], 0.f);
        o1.z = fmaxf((b2f(v[6]) - lmu[cb + 6]) * lrs[cb + 6], 0.f);
        o1.w = fmaxf((b2f(v[7]) - lmu[cb + 7]) * lrs[cb + 7], 0.f);
        reinterpret_cast<float4*>(Out)[i * 2] = o0;
        reinterpret_cast<float4*>(Out)[i * 2 + 1] = o1;
    }
}

// ---------- max-pool raw conv2 output, then normalize+relu -> bf16 ----------
// valid: inst_norm (rstd>0) and relu are monotone increasing -> pool/norm commute
__global__ __launch_bounds__(256) void pool_norm_kernel(const unsigned short* __restrict__ Y2,
                                                        const int* __restrict__ pmap,
                                                        const float* __restrict__ sums,
                                                        unsigned short* __restrict__ Xp,
                                                        int M, int R) {
    __shared__ float lmu[64], lrs[64];
    if (threadIdx.x < 64) {
        float m = sums[threadIdx.x] / (float)R;
        float v = sums[64 + threadIdx.x] / (float)R - m * m;
        lmu[threadIdx.x] = m;
        lrs[threadIdx.x] = rsqrtf(fmaxf(v, 0.f) + 1e-5f);
    }
    __syncthreads();
    const int lane = threadIdx.x & 63;
    const int gw = blockIdx.x * 4 + (threadIdx.x >> 6);
    const int nw = gridDim.x * 4;
    for (int m = gw; m < M; m += nw) {
        int idx[8];
        #pragma unroll
        for (int o = 0; o < 8; ++o) idx[o] = pmap[o * M + m];   // all 8 issued up-front
        float best = -INFINITY;
        #pragma unroll
        for (int o = 0; o < 8; ++o)
            if (idx[o] >= 0) best = fmaxf(best, b2f(Y2[idx[o] * 64 + lane]));  // wave-uniform
        Xp[m * 64 + lane] = f2b(fmaxf((best - lmu[lane]) * lrs[lane], 0.f));
    }
}

extern "C" void kernel_launch(void* const* d_in, const int* in_sizes, int n_in,
                              void* d_out, int out_size, void* d_ws, size_t ws_size,
                              hipStream_t stream) {
    const float* feats = (const float*)d_in[0];
    const float* W1 = (const float*)d_in[1];
    const float* W2 = (const float*)d_in[2];
    const float* W3 = (const float*)d_in[3];
    const int* nbr1 = (const int*)d_in[4];
    const int* pmap = (const int*)d_in[5];
    const int* nbr2 = (const int*)d_in[6];
    float* out = (float*)d_out;

    const int N = N_FULL, M = M_POOL;
    char* ws = (char*)d_ws;
    unsigned short* yb = (unsigned short*)ws;              // bf16 N*64 (y1,y2,y3)
    unsigned short* xb = yb + (size_t)N * 64;              // bf16 N*64 (x1, pooled x)
    unsigned short* w1p = xb + (size_t)N * 64;
    unsigned short* w2p = w1p + 7 * 4 * 64 * 8;
    unsigned short* w3p = w2p + 27 * 64 * 64;
    float* sums = (float*)(w3p + 27 * 64 * 128);
    float* sums1 = sums;
    float* sums2 = sums + 128;
    float* sums3 = sums + 256;

    hipMemsetAsync(sums, 0, 512 * sizeof(float), stream);
    pack_w1_kernel<<<(7 * 2048 + 255) / 256, 256, 0, stream>>>(W1, w1p);
    pack_w_kernel<4><<<(27 * 4096 + 255) / 256, 256, 0, stream>>>(W2, w2p);
    pack_w_kernel<8><<<(27 * 8192 + 255) / 256, 256, 0, stream>>>(W3, w3p);

    conv1_mfma_kernel<<<N / 128, 256, 0, stream>>>(feats, w1p, nbr1, yb, sums1, N);
    norm_bf16_kernel<64><<<2048, 256, 0, stream>>>(yb, sums1, xb, N);

    conv_mfma_kernel<4><<<N / 128, 256, 0, stream>>>(xb, w2p, nbr1, yb, sums2, N);
    pool_norm_kernel<<<2048, 256, 0, stream>>>(yb, pmap, sums2, xb, M, N);

    conv_mfma_kernel<8><<<M / 128, 256, 0, stream>>>(xb, w3p, nbr2, yb, sums3, M);
    norm_f32_kernel<128><<<2048, 256, 0, stream>>>(yb, sums3, out, M);
}

// Round 4
// 386.118 us; speedup vs baseline: 1.3924x; 1.3924x over previous
//
#include <hip/hip_runtime.h>
#include <hip/hip_bf16.h>

#define N_FULL 262144
#define M_POOL 131072

typedef __attribute__((ext_vector_type(4))) float f32x4;
typedef __attribute__((ext_vector_type(8))) short bf16x8;
typedef __attribute__((ext_vector_type(8))) unsigned short u16x8;

static __device__ __forceinline__ unsigned short f2b(float f) {
    __hip_bfloat16 b = __float2bfloat16(f);
    return *reinterpret_cast<unsigned short*>(&b);
}
static __device__ __forceinline__ float b2f(unsigned short u) {
    unsigned int x = ((unsigned int)u) << 16;
    return __uint_as_float(x);
}

// async global->LDS, 16B per lane; l must be wave-uniform (HW adds lane*16)
static __device__ __forceinline__ void gll16(const void* g, void* l) {
    __builtin_amdgcn_global_load_lds(
        (const __attribute__((address_space(1))) void*)g,
        (__attribute__((address_space(3))) void*)l, 16, 0, 0);
}

// ---------- pack W2/W3 into MFMA B-fragment order, zero-padded to NPT taps ----------
// Wp[k][q][t][lane][j] = W[k][q*32 + (lane>>4)*8 + j][t*16 + (lane&15)], 0 for k>=27
template<int CT, int NPT>
__global__ __launch_bounds__(256) void pack_w_kernel(const float* __restrict__ W,
                                                     unsigned short* __restrict__ Wp) {
    int i = blockIdx.x * 256 + threadIdx.x;
    const int total = NPT * 2 * CT * 64 * 8;
    if (i >= total) return;
    int j = i & 7;
    int l = (i >> 3) & 63;
    int t = (i >> 9) % CT;
    int q = (i / (512 * CT)) & 1;
    int k = i / (1024 * CT);
    int cin = q * 32 + (l >> 4) * 8 + j;
    int cout = t * 16 + (l & 15);
    float v = (k < 27) ? W[(k * 64 + cin) * (CT * 16) + cout] : 0.f;
    Wp[i] = f2b(v);
}

// ---------- pack W1 (Cin=3) with 4 taps folded into K=32 (zero pad tap 27) ----------
__global__ __launch_bounds__(256) void pack_w1_kernel(const float* __restrict__ W1,
                                                      unsigned short* __restrict__ Wp) {
    int i = blockIdx.x * 256 + threadIdx.x;
    const int total = 7 * 4 * 64 * 8;
    if (i >= total) return;
    int j = i & 7;
    int l = (i >> 3) & 63;
    int t = (i >> 9) & 3;
    int kb = i >> 11;
    int tap = kb * 4 + (l >> 4);
    float v = 0.f;
    if (tap < 27 && j < 3) v = W1[(tap * 3 + j) * 64 + t * 16 + (l & 15)];
    Wp[i] = f2b(v);
}

// ---------- conv1: MFMA, 4 taps per K=32, ONE staging phase, fused stats ----------
__global__ __launch_bounds__(256) void conv1_mfma_kernel(const float* __restrict__ feats,
                                                         const unsigned short* __restrict__ Wp,
                                                         const int* __restrict__ nbr,
                                                         unsigned short* __restrict__ Y,
                                                         float* __restrict__ sums, int R) {
    __shared__ unsigned short lw[7 * 2048];          // 28 KB: all packed W1
    __shared__ float psum[4][64], psq[4][64];
    const int tid = threadIdx.x;
    const int wave = tid >> 6;
    const int lane = tid & 63;
    const int l16 = lane & 15;
    const int lq = lane >> 4;
    const int rowbase = blockIdx.x * 128 + wave * 32;

    // stage all of W1p: 28 chunks of 1KB, 7 per wave
    {
        const char* gsrc = (const char*)Wp;
        char* lbase = (char*)lw;
        #pragma unroll
        for (int c = 0; c < 7; ++c) {
            int off = (wave * 7 + c) * 1024;
            gll16(gsrc + off + lane * 16, lbase + off);
        }
    }
    // all idx loads (tap = g*4+lq; tap 27 masked)
    int idx[7][2];
    #pragma unroll
    for (int g = 0; g < 7; ++g) {
        int tap = g * 4 + lq;
        #pragma unroll
        for (int s = 0; s < 2; ++s)
            idx[g][s] = (tap < 27) ? nbr[(size_t)tap * R + rowbase + s * 16 + l16] : -1;
    }
    __syncthreads();   // drains staging + idx

    f32x4 acc[2][4];
    #pragma unroll
    for (int s = 0; s < 2; ++s)
        #pragma unroll
        for (int t = 0; t < 4; ++t)
            #pragma unroll
            for (int g = 0; g < 4; ++g) acc[s][t][g] = 0.f;
    bf16x8 zf;
    #pragma unroll
    for (int j = 0; j < 8; ++j) zf[j] = 0;

    // gather all A fragments (predicated; compiler emits counted vmcnt before uses)
    bf16x8 af[7][2];
    #pragma unroll
    for (int g = 0; g < 7; ++g)
        #pragma unroll
        for (int s = 0; s < 2; ++s) {
            af[g][s] = zf;
            int ic = idx[g][s];
            if (ic >= 0) {
                af[g][s][0] = (short)f2b(feats[ic * 3 + 0]);
                af[g][s][1] = (short)f2b(feats[ic * 3 + 1]);
                af[g][s][2] = (short)f2b(feats[ic * 3 + 2]);
            }
        }
    #pragma unroll
    for (int g = 0; g < 7; ++g) {
        #pragma unroll
        for (int t = 0; t < 4; ++t) {
            bf16x8 bfr = *reinterpret_cast<const bf16x8*>(&lw[g * 2048 + t * 512 + lane * 8]);
            #pragma unroll
            for (int s = 0; s < 2; ++s)
                acc[s][t] = __builtin_amdgcn_mfma_f32_16x16x32_bf16(af[g][s], bfr, acc[s][t], 0, 0, 0);
        }
    }
    // store bf16 + fused stats
    #pragma unroll
    for (int t = 0; t < 4; ++t) {
        float s1 = 0.f, s2 = 0.f;
        #pragma unroll
        for (int s = 0; s < 2; ++s)
            #pragma unroll
            for (int g = 0; g < 4; ++g) {
                float v = acc[s][t][g];
                s1 += v; s2 += v * v;
                Y[(size_t)(rowbase + s * 16 + lq * 4 + g) * 64 + t * 16 + l16] = f2b(v);
            }
        s1 += __shfl_xor(s1, 16); s2 += __shfl_xor(s2, 16);
        s1 += __shfl_xor(s1, 32); s2 += __shfl_xor(s2, 32);
        if (lq == 0) { psum[wave][t * 16 + l16] = s1; psq[wave][t * 16 + l16] = s2; }
    }
    __syncthreads();
    if (tid < 64) {
        float s1 = 0.f, s2 = 0.f;
        #pragma unroll
        for (int w = 0; w < 4; ++w) { s1 += psum[w][tid]; s2 += psq[w][tid]; }
        atomicAdd(&sums[tid], s1);
        atomicAdd(&sums[64 + tid], s2);
    }
}

// ---------- MFMA sparse conv: Cin=64, Cout=CT*16, TCH taps per barrier-pair ----------
// NPT = padded tap count (multiple of TCH, weights zero-padded)
template<int CT, int TCH, int NPT>
__global__ __launch_bounds__(256) void conv_mfma_kernel(const unsigned short* __restrict__ X,
                                                        const unsigned short* __restrict__ Wp,
                                                        const int* __restrict__ nbr,
                                                        unsigned short* __restrict__ Y,
                                                        float* __restrict__ sums, int Nout) {
    constexpr int C = CT * 16;
    constexpr int NPH = NPT / TCH;
    constexpr int TAPB = 2 * CT * 512;               // u16 per tap
    __shared__ unsigned short lw[TCH * TAPB];        // TCH*CT*2 KB (48 KB both convs)
    __shared__ float psum[4][C], psq[4][C];
    const int tid = threadIdx.x;
    const int wave = tid >> 6;
    const int lane = tid & 63;
    const int l16 = lane & 15;
    const int lq = lane >> 4;
    const int rowbase = blockIdx.x * 128 + wave * 32;

    f32x4 acc[2][CT];
    #pragma unroll
    for (int s = 0; s < 2; ++s)
        #pragma unroll
        for (int t = 0; t < CT; ++t)
            #pragma unroll
            for (int g = 0; g < 4; ++g) acc[s][t][g] = 0.f;
    bf16x8 zf;
    #pragma unroll
    for (int j = 0; j < 8; ++j) zf[j] = 0;

    // prolog: idx for phase 0 (taps 0..TCH-1, all < 27)
    int idxp[TCH][2];
    #pragma unroll
    for (int t = 0; t < TCH; ++t)
        #pragma unroll
        for (int s = 0; s < 2; ++s)
            idxp[t][s] = nbr[(size_t)t * Nout + rowbase + s * 16 + l16];

    for (int ph = 0; ph < NPH; ++ph) {
        if (ph) __syncthreads();   // lw overwrite guard (no outstanding vmem here -> cheap)
        // stage TCH taps of B: TCH*CT*2048 bytes, split 4 waves x (TCH*CT/2) KB-chunks
        {
            const char* gseg = (const char*)Wp + (size_t)ph * TCH * TAPB * 2;
            char* lbase = (char*)lw;
            const int woff = wave * (TCH * TAPB * 2 / 4);
            #pragma unroll
            for (int c = 0; c < TCH * CT / 2; ++c) {
                int off = woff + c * 1024;
                gll16(gseg + off + lane * 16, lbase + off);
            }
        }
        // gather this phase's A fragments (idx values already resident)
        bf16x8 af[TCH][2][2];
        #pragma unroll
        for (int t = 0; t < TCH; ++t)
            #pragma unroll
            for (int s = 0; s < 2; ++s) {
                int ic = idxp[t][s];
                #pragma unroll
                for (int q = 0; q < 2; ++q) af[t][s][q] = zf;
                if (ic >= 0) {
                    #pragma unroll
                    for (int q = 0; q < 2; ++q)
                        af[t][s][q] = *reinterpret_cast<const bf16x8*>(
                            X + (size_t)ic * 64 + q * 32 + lq * 8);
                }
            }
        // issue next phase's idx loads
        int idxn[TCH][2];
        #pragma unroll
        for (int t = 0; t < TCH; ++t) {
            int tap = (ph + 1) * TCH + t;
            #pragma unroll
            for (int s = 0; s < 2; ++s)
                idxn[t][s] = (tap < 27) ? nbr[(size_t)tap * Nout + rowbase + s * 16 + l16] : -1;
        }
        __syncthreads();   // one wide drain: staging + gathers + idx
        // compute TCH taps (LDS + MFMA only)
        #pragma unroll
        for (int t = 0; t < TCH; ++t) {
            #pragma unroll
            for (int q = 0; q < 2; ++q) {
                #pragma unroll
                for (int tt = 0; tt < CT; ++tt) {
                    bf16x8 bfr = *reinterpret_cast<const bf16x8*>(
                        &lw[t * TAPB + (q * CT + tt) * 512 + lane * 8]);
                    #pragma unroll
                    for (int s = 0; s < 2; ++s)
                        acc[s][tt] = __builtin_amdgcn_mfma_f32_16x16x32_bf16(
                            af[t][s][q], bfr, acc[s][tt], 0, 0, 0);
                }
            }
        }
        #pragma unroll
        for (int t = 0; t < TCH; ++t)
            #pragma unroll
            for (int s = 0; s < 2; ++s) idxp[t][s] = idxn[t][s];
    }
    // epilogue: D layout col=lane&15, row=(lane>>4)*4+g; fused stats
    #pragma unroll
    for (int t = 0; t < CT; ++t) {
        float s1 = 0.f, s2 = 0.f;
        #pragma unroll
        for (int s = 0; s < 2; ++s)
            #pragma unroll
            for (int g = 0; g < 4; ++g) {
                float v = acc[s][t][g];
                s1 += v; s2 += v * v;
                Y[(size_t)(rowbase + s * 16 + lq * 4 + g) * C + t * 16 + l16] = f2b(v);
            }
        s1 += __shfl_xor(s1, 16); s2 += __shfl_xor(s2, 16);
        s1 += __shfl_xor(s1, 32); s2 += __shfl_xor(s2, 32);
        if (lq == 0) { psum[wave][t * 16 + l16] = s1; psq[wave][t * 16 + l16] = s2; }
    }
    __syncthreads();
    if (tid < C) {
        float s1 = 0.f, s2 = 0.f;
        #pragma unroll
        for (int w = 0; w < 4; ++w) { s1 += psum[w][tid]; s2 += psq[w][tid]; }
        atomicAdd(&sums[tid], s1);
        atomicAdd(&sums[C + tid], s2);
    }
}

// ---------- normalize + relu : bf16 in -> bf16 out ----------
template<int C>
__global__ __launch_bounds__(256) void norm_bf16_kernel(const unsigned short* __restrict__ Y,
                                                        const float* __restrict__ sums,
                                                        unsigned short* __restrict__ Xb, int R) {
    __shared__ float lmu[C], lrs[C];
    if (threadIdx.x < C) {
        float m = sums[threadIdx.x] / (float)R;
        float v = sums[C + threadIdx.x] / (float)R - m * m;
        lmu[threadIdx.x] = m;
        lrs[threadIdx.x] = rsqrtf(fmaxf(v, 0.f) + 1e-5f);
    }
    __syncthreads();
    const int total = R * C / 8;
    for (int i = blockIdx.x * 256 + threadIdx.x; i < total; i += gridDim.x * 256) {
        u16x8 v = reinterpret_cast<const u16x8*>(Y)[i];
        int cb = (i * 8) & (C - 1);
        u16x8 o;
        #pragma unroll
        for (int j = 0; j < 8; ++j) {
            float f = b2f(v[j]);
            o[j] = f2b(fmaxf((f - lmu[cb + j]) * lrs[cb + j], 0.f));
        }
        reinterpret_cast<u16x8*>(Xb)[i] = o;
    }
}

// ---------- normalize + relu : bf16 in -> f32 out (final) ----------
template<int C>
__global__ __launch_bounds__(256) void norm_f32_kernel(const unsigned short* __restrict__ Y,
                                                       const float* __restrict__ sums,
                                                       float* __restrict__ Out, int R) {
    __shared__ float lmu[C], lrs[C];
    if (threadIdx.x < C) {
        float m = sums[threadIdx.x] / (float)R;
        float v = sums[C + threadIdx.x] / (float)R - m * m;
        lmu[threadIdx.x] = m;
        lrs[threadIdx.x] = rsqrtf(fmaxf(v, 0.f) + 1e-5f);
    }
    __syncthreads();
    const int total = R * C / 8;
    for (int i = blockIdx.x * 256 + threadIdx.x; i < total; i += gridDim.x * 256) {
        u16x8 v = reinterpret_cast<const u16x8*>(Y)[i];
        int cb = (i * 8) & (C - 1);
        float4 o0, o1;
        o0.x = fmaxf((b2f(v[0]) - lmu[cb + 0]) * lrs[cb + 0], 0.f);
        o0.y = fmaxf((b2f(v[1]) - lmu[cb + 1]) * lrs[cb + 1], 0.f);
        o0.z = fmaxf((b2f(v[2]) - lmu[cb + 2]) * lrs[cb + 2], 0.f);
        o0.w = fmaxf((b2f(v[3]) - lmu[cb + 3]) * lrs[cb + 3], 0.f);
        o1.x = fmaxf((b2f(v[4]) - lmu[cb + 4]) * lrs[cb + 4], 0.f);
        o1.y = fmaxf((b2f(v[5]) - lmu[cb + 5]) * lrs[cb + 5], 0.f);
        o1.z = fmaxf((b2f(v[6]) - lmu[cb + 6]) * lrs[cb + 6], 0.f);
        o1.w = fmaxf((b2f(v[7]) - lmu[cb + 7]) * lrs[cb + 7], 0.f);
        reinterpret_cast<float4*>(Out)[i * 2] = o0;
        reinterpret_cast<float4*>(Out)[i * 2 + 1] = o1;
    }
}

// ---------- max-pool raw conv2 output, then normalize+relu -> bf16 ----------
// valid: inst_norm (rstd>0) and relu are monotone increasing -> pool/norm commute
__global__ __launch_bounds__(256) void pool_norm_kernel(const unsigned short* __restrict__ Y2,
                                                        const int* __restrict__ pmap,
                                                        const float* __restrict__ sums,
                                                        unsigned short* __restrict__ Xp,
                                                        int M, int R) {
    __shared__ float lmu[64], lrs[64];
    if (threadIdx.x < 64) {
        float m = sums[threadIdx.x] / (float)R;
        float v = sums[64 + threadIdx.x] / (float)R - m * m;
        lmu[threadIdx.x] = m;
        lrs[threadIdx.x] = rsqrtf(fmaxf(v, 0.f) + 1e-5f);
    }
    __syncthreads();
    const int lane = threadIdx.x & 63;
    const int gw = blockIdx.x * 4 + (threadIdx.x >> 6);
    const int nw = gridDim.x * 4;
    for (int m = gw; m < M; m += nw) {
        int idx[8];
        #pragma unroll
        for (int o = 0; o < 8; ++o) idx[o] = pmap[o * M + m];
        float best = -INFINITY;
        #pragma unroll
        for (int o = 0; o < 8; ++o)
            if (idx[o] >= 0) best = fmaxf(best, b2f(Y2[(size_t)idx[o] * 64 + lane]));
        Xp[(size_t)m * 64 + lane] = f2b(fmaxf((best - lmu[lane]) * lrs[lane], 0.f));
    }
}

extern "C" void kernel_launch(void* const* d_in, const int* in_sizes, int n_in,
                              void* d_out, int out_size, void* d_ws, size_t ws_size,
                              hipStream_t stream) {
    const float* feats = (const float*)d_in[0];
    const float* W1 = (const float*)d_in[1];
    const float* W2 = (const float*)d_in[2];
    const float* W3 = (const float*)d_in[3];
    const int* nbr1 = (const int*)d_in[4];
    const int* pmap = (const int*)d_in[5];
    const int* nbr2 = (const int*)d_in[6];
    float* out = (float*)d_out;

    const int N = N_FULL, M = M_POOL;
    char* ws = (char*)d_ws;
    unsigned short* yb = (unsigned short*)ws;              // bf16 N*64 (y1,y2,y3)
    unsigned short* xb = yb + (size_t)N * 64;              // bf16 N*64 (x1, pooled x)
    unsigned short* w1p = xb + (size_t)N * 64;             // 7*4*64*8
    unsigned short* w2p = w1p + 7 * 4 * 64 * 8;            // 30 taps padded
    unsigned short* w3p = w2p + 30 * 2 * 4 * 512;          // 27 taps
    float* sums = (float*)(w3p + 27 * 2 * 8 * 512);
    float* sums1 = sums;
    float* sums2 = sums + 128;
    float* sums3 = sums + 256;

    hipMemsetAsync(sums, 0, 512 * sizeof(float), stream);
    pack_w1_kernel<<<(7 * 2048 + 255) / 256, 256, 0, stream>>>(W1, w1p);
    pack_w_kernel<4, 30><<<(30 * 4096 + 255) / 256, 256, 0, stream>>>(W2, w2p);
    pack_w_kernel<8, 27><<<(27 * 8192 + 255) / 256, 256, 0, stream>>>(W3, w3p);

    conv1_mfma_kernel<<<N / 128, 256, 0, stream>>>(feats, w1p, nbr1, yb, sums1, N);
    norm_bf16_kernel<64><<<2048, 256, 0, stream>>>(yb, sums1, xb, N);

    conv_mfma_kernel<4, 6, 30><<<N / 128, 256, 0, stream>>>(xb, w2p, nbr1, yb, sums2, N);
    pool_norm_kernel<<<2048, 256, 0, stream>>>(yb, pmap, sums2, xb, M, N);

    conv_mfma_kernel<8, 3, 27><<<M / 128, 256, 0, stream>>>(xb, w3p, nbr2, yb, sums3, M);
    norm_f32_kernel<128><<<2048, 256, 0, stream>>>(yb, sums3, out, M);
}